// Round 10
// baseline (482.953 us; speedup 1.0000x reference)
//
#include <hip/hip_runtime.h>
#include <math.h>

#define NN 100000
#define DD 128
#define CC 64
#define TT 8
#define NS 50000
#define G8 8
#define MAXS2 196                 // ceil(NS/256)
#define TOTW (G8 * MAXS2)         // 1568

typedef __attribute__((ext_vector_type(4))) float f32x4;
typedef __attribute__((ext_vector_type(8))) short bf16x8;
typedef unsigned short ushort_t;

__device__ __forceinline__ short f2bf(float f) {
    union { float f; unsigned u; } v; v.f = f;
    unsigned r = v.u + 0x7fffu + ((v.u >> 16) & 1u);
    return (short)(r >> 16);
}
__device__ __forceinline__ unsigned pk_bf16(float lo, float hi) {
    unsigned r;
    asm("v_cvt_pk_bf16_f32 %0, %1, %2" : "=v"(r) : "v"(lo), "v"(hi));
    return r;
}
// tanh-form GELU via hardware exp: max |diff| vs exact erf-GELU ~3e-3
__device__ __forceinline__ float gelu(float x) {
    float t = x + 0.044715f * x * x * x;
    return x / (1.0f + __expf(-1.5957691216f * t));
}

// ---------------- all four weights -> MFMA-fragment tables ----------------
__global__ void prep_all(const float* __restrict__ Wd1, const float* __restrict__ Wd2,
                         const float* __restrict__ Wu1, const float* __restrict__ Wu2,
                         short* __restrict__ pW1, short* __restrict__ pW2,
                         short* __restrict__ pW3, short* __restrict__ pW4) {
    int b = blockIdx.x;
    const float* W; short* dst; int KSTEPS, total, N, s0;
    if (b < 16)      { W = Wd1; dst = pW1; KSTEPS = 4; total = 4096; N = 256; s0 = b * 256; }
    else if (b < 24) { W = Wd2; dst = pW2; KSTEPS = 8; total = 2048; N = 64;  s0 = (b - 16) * 256; }
    else if (b < 28) { W = Wu1; dst = pW3; KSTEPS = 2; total = 1024; N = 128; s0 = (b - 24) * 256; }
    else             { W = Wu2; dst = pW4; KSTEPS = 4; total = 2048; N = 128; s0 = (b - 28) * 256; }
    int s = s0 + threadIdx.x;
    if (s >= total) return;
    int lane = s & 63;
    int ks = (s >> 6) % KSTEPS;
    int n = s / (64 * KSTEPS);
    int kb = ks * 32 + (lane >> 4) * 8;
    int col = n * 16 + (lane & 15);
    bf16x8 o;
    #pragma unroll
    for (int j = 0; j < 8; ++j) o[j] = f2bf(W[(size_t)(kb + j) * N + col]);
    *(bf16x8*)(dst + (size_t)s * 8) = o;
}

// -------- count + record contributor positions (packed u16 buckets) --------
__global__ void flagfill_kernel(const int* __restrict__ idx, int* __restrict__ pernode,
                                ushort_t* __restrict__ bucket) {
    int i = blockIdx.x * 256 + threadIdx.x;
    if (i >= G8 * NS) return;
    int g = i / NS, s = i - g * NS;
    int node = idx[i];
    int p = atomicAdd(&pernode[node * 8 + g], 1);
    if (p < 16) bucket[((size_t)node * 8 + g) * 16 + p] = (ushort_t)s;
}

// ------- active lists (wave-aggregated atomics) -----------------------------
__global__ void compact_kernel(const int* __restrict__ pernode,
                               int* __restrict__ lists, int* __restrict__ cnts) {
    int g = blockIdx.y;
    int node = blockIdx.x * 256 + threadIdx.x;
    bool active = (node < NN) && (pernode[node * 8 + g] > 0);
    unsigned long long m = __ballot(active);
    int lane = threadIdx.x & 63;
    int rank = __popcll(m & ((1ull << lane) - 1ull));
    int nact = __popcll(m);
    int lbase = 0;
    if (lane == 0 && nact > 0) lbase = atomicAdd(&cnts[g], nact);
    lbase = __shfl(lbase, 0);
    if (active) lists[(size_t)g * NS + lbase + rank] = node;
}

// ---- fully fused per unique node; 1024 threads = 16 waves, 16 nodes/wave.
// LDS: W1 64K + W2 32K + W4 32K + 16x2K wave buffers = 160KB; W3 from L2.
// Meta (list->pernode/bucket) software-pipelined one iteration ahead.
__global__ __launch_bounds__(1024, 4) void fused_kernel(
    const float* __restrict__ x, const float* __restrict__ bd,
    const float* __restrict__ lndg, const float* __restrict__ lndb,
    const short* __restrict__ pW1, const short* __restrict__ pW2,
    const short* __restrict__ pW3, const short* __restrict__ pW4,
    const float* __restrict__ bd1, const float* __restrict__ bd2,
    const float* __restrict__ lnug, const float* __restrict__ lnub,
    const float* __restrict__ bu1, const float* __restrict__ bu2,
    const int* __restrict__ lists, const int* __restrict__ cnts,
    const int* __restrict__ pernode, const ushort_t* __restrict__ bucket,
    float* __restrict__ out) {
    __shared__ short sW1[4096 * 8];
    __shared__ short sW2[2048 * 8];
    __shared__ short sW4[2048 * 8];
    __shared__ short sBuf[16][1024];   // 2KB per wave

    const int tid = threadIdx.x;
    for (int s = tid; s < 4096; s += 1024)
        *(bf16x8*)(sW1 + s * 8) = *(const bf16x8*)(pW1 + (size_t)s * 8);
    for (int s = tid; s < 2048; s += 1024)
        *(bf16x8*)(sW2 + s * 8) = *(const bf16x8*)(pW2 + (size_t)s * 8);
    for (int s = tid; s < 2048; s += 1024)
        *(bf16x8*)(sW4 + s * 8) = *(const bf16x8*)(pW4 + (size_t)s * 8);
    __syncthreads();

    const int wave = tid >> 6, lane = tid & 63;
    short* myb = sBuf[wave];
    const int arow = lane & 15;
    const int kgrp = lane >> 4;

    // ---- pipeline prologue: meta for first tile
    int w = blockIdx.x;
    int node_c = 0, c_c = 0;
    int4 p8_c = {0, 0, 0, 0};
    {
        int g0 = w & 7, strip0 = w >> 3;
        int gi0 = strip0 * 256 + wave * 16 + arow;
        int li0 = gi0 < NS ? gi0 : NS - 1;
        node_c = lists[(size_t)g0 * NS + li0];
        c_c = pernode[node_c * 8 + g0];
        p8_c = *(const int4*)(bucket + ((size_t)node_c * 8 + g0) * 16);
    }

    for (; w < TOTW; w += gridDim.x) {
        const int g = w & 7, strip = w >> 3;
        const int nrows = cnts[g];
        const int row0 = strip * 256 + wave * 16;
        const float* x_g = x + (size_t)g * NS * DD;
        float* out_g = out + (size_t)g * NS * DD;

        // ---- issue next tile's list load (independent of this tile)
        const int wn = w + gridDim.x;
        const bool hn = wn < TOTW;
        const int gn = hn ? (wn & 7) : 0;
        const int stripn = hn ? (wn >> 3) : 0;
        int gin = stripn * 256 + wave * 16 + arow;
        int lin = gin < NS ? gin : NS - 1;
        const int node_n = lists[(size_t)gn * NS + lin];
        int c_n;
        int4 p8_n;

        if (strip * 256 < nrows) {
            const int c = c_c;
            const int pr0 = p8_c.x & 0xffff, pr1 = ((unsigned)p8_c.x) >> 16;
            const int pr2 = p8_c.y & 0xffff, pr3 = ((unsigned)p8_c.y) >> 16;
            // ---- gather + bd, incremental accumulation (low VGPR pressure)
            float v[32];
            {
                const float* bp = bd + (size_t)node_c * DD + kgrp * 8;
                const float* xq0 = x_g + (size_t)pr0 * DD + kgrp * 8;
                const float* xq1 = x_g + (size_t)((c > 1) ? pr1 : pr0) * DD + kgrp * 8;
                const float m1 = (c > 1) ? 1.f : 0.f;
                #pragma unroll
                for (int ks = 0; ks < 4; ++ks) {
                    float4 b0 = *(const float4*)(bp + ks * 32);
                    float4 b1 = *(const float4*)(bp + ks * 32 + 4);
                    float4 a0 = *(const float4*)(xq0 + ks * 32);
                    float4 a1 = *(const float4*)(xq0 + ks * 32 + 4);
                    float4 d0 = *(const float4*)(xq1 + ks * 32);
                    float4 d1 = *(const float4*)(xq1 + ks * 32 + 4);
                    v[ks*8+0] = fmaf(m1, d0.x, b0.x + a0.x);
                    v[ks*8+1] = fmaf(m1, d0.y, b0.y + a0.y);
                    v[ks*8+2] = fmaf(m1, d0.z, b0.z + a0.z);
                    v[ks*8+3] = fmaf(m1, d0.w, b0.w + a0.w);
                    v[ks*8+4] = fmaf(m1, d1.x, b1.x + a1.x);
                    v[ks*8+5] = fmaf(m1, d1.y, b1.y + a1.y);
                    v[ks*8+6] = fmaf(m1, d1.z, b1.z + a1.z);
                    v[ks*8+7] = fmaf(m1, d1.w, b1.w + a1.w);
                }
            }
            if (__any(c > 2)) {   // ~44% of waves
                const float* xq2 = x_g + (size_t)((c > 2) ? pr2 : pr0) * DD + kgrp * 8;
                const float* xq3 = x_g + (size_t)((c > 3) ? pr3 : pr0) * DD + kgrp * 8;
                const float m2 = (c > 2) ? 1.f : 0.f;
                const float m3 = (c > 3) ? 1.f : 0.f;
                #pragma unroll
                for (int ks = 0; ks < 4; ++ks) {
                    float4 a0 = *(const float4*)(xq2 + ks * 32);
                    float4 a1 = *(const float4*)(xq2 + ks * 32 + 4);
                    float4 d0 = *(const float4*)(xq3 + ks * 32);
                    float4 d1 = *(const float4*)(xq3 + ks * 32 + 4);
                    v[ks*8+0] = fmaf(m3, d0.x, fmaf(m2, a0.x, v[ks*8+0]));
                    v[ks*8+1] = fmaf(m3, d0.y, fmaf(m2, a0.y, v[ks*8+1]));
                    v[ks*8+2] = fmaf(m3, d0.z, fmaf(m2, a0.z, v[ks*8+2]));
                    v[ks*8+3] = fmaf(m3, d0.w, fmaf(m2, a0.w, v[ks*8+3]));
                    v[ks*8+4] = fmaf(m3, d1.x, fmaf(m2, a1.x, v[ks*8+4]));
                    v[ks*8+5] = fmaf(m3, d1.y, fmaf(m2, a1.y, v[ks*8+5]));
                    v[ks*8+6] = fmaf(m3, d1.z, fmaf(m2, a1.z, v[ks*8+6]));
                    v[ks*8+7] = fmaf(m3, d1.w, fmaf(m2, a1.w, v[ks*8+7]));
                }
            }
            if (__any(c > 4)) {   // ~0.7% of waves
                const int pr4 = p8_c.z & 0xffff, pr5 = ((unsigned)p8_c.z) >> 16;
                const int pr6 = p8_c.w & 0xffff, pr7 = ((unsigned)p8_c.w) >> 16;
                const float* xq4 = x_g + (size_t)((c > 4) ? pr4 : pr0) * DD + kgrp * 8;
                const float* xq5 = x_g + (size_t)((c > 5) ? pr5 : pr0) * DD + kgrp * 8;
                const float* xq6 = x_g + (size_t)((c > 6) ? pr6 : pr0) * DD + kgrp * 8;
                const float* xq7 = x_g + (size_t)((c > 7) ? pr7 : pr0) * DD + kgrp * 8;
                const float m4 = (c > 4) ? 1.f : 0.f;
                const float m5 = (c > 5) ? 1.f : 0.f;
                const float m6 = (c > 6) ? 1.f : 0.f;
                const float m7 = (c > 7) ? 1.f : 0.f;
                #pragma unroll
                for (int ks = 0; ks < 4; ++ks) {
                    float4 a0 = *(const float4*)(xq4 + ks * 32);
                    float4 a1 = *(const float4*)(xq4 + ks * 32 + 4);
                    float4 d0 = *(const float4*)(xq5 + ks * 32);
                    float4 d1 = *(const float4*)(xq5 + ks * 32 + 4);
                    float4 e0 = *(const float4*)(xq6 + ks * 32);
                    float4 e1 = *(const float4*)(xq6 + ks * 32 + 4);
                    float4 f0 = *(const float4*)(xq7 + ks * 32);
                    float4 f1 = *(const float4*)(xq7 + ks * 32 + 4);
                    #pragma unroll
                    for (int q = 0; q < 4; ++q) {
                        float av = (&a0.x)[q], dv = (&d0.x)[q], ev = (&e0.x)[q], fv = (&f0.x)[q];
                        v[ks*8+q] = fmaf(m7, fv, fmaf(m6, ev, fmaf(m5, dv, fmaf(m4, av, v[ks*8+q]))));
                        float av1 = (&a1.x)[q], dv1 = (&d1.x)[q], ev1 = (&e1.x)[q], fv1 = (&f1.x)[q];
                        v[ks*8+4+q] = fmaf(m7, fv1, fmaf(m6, ev1, fmaf(m5, dv1, fmaf(m4, av1, v[ks*8+4+q]))));
                    }
                }
            }
            if (__any(c > 8)) {   // ultra-rare correctness path
                const ushort_t* bt = bucket + ((size_t)node_c * 8 + g) * 16;
                for (int j = 8; j < 16; ++j) {
                    const int pj = (j < c) ? bt[j] : pr0;
                    const float mj = (j < c) ? 1.f : 0.f;
                    const float* xq = x_g + (size_t)pj * DD + kgrp * 8;
                    #pragma unroll
                    for (int ks = 0; ks < 4; ++ks) {
                        float4 a0 = *(const float4*)(xq + ks * 32);
                        float4 a1 = *(const float4*)(xq + ks * 32 + 4);
                        v[ks*8+0] = fmaf(mj, a0.x, v[ks*8+0]);
                        v[ks*8+1] = fmaf(mj, a0.y, v[ks*8+1]);
                        v[ks*8+2] = fmaf(mj, a0.z, v[ks*8+2]);
                        v[ks*8+3] = fmaf(mj, a0.w, v[ks*8+3]);
                        v[ks*8+4] = fmaf(mj, a1.x, v[ks*8+4]);
                        v[ks*8+5] = fmaf(mj, a1.y, v[ks*8+5]);
                        v[ks*8+6] = fmaf(mj, a1.z, v[ks*8+6]);
                        v[ks*8+7] = fmaf(mj, a1.w, v[ks*8+7]);
                    }
                }
            }
            // ---- LN_d
            float s1 = 0.f;
            #pragma unroll
            for (int j = 0; j < 32; ++j) s1 += v[j];
            s1 += __shfl_xor(s1, 16); s1 += __shfl_xor(s1, 32);
            float mu = s1 * 0.0078125f;
            float s2 = 0.f;
            #pragma unroll
            for (int j = 0; j < 32; ++j) { float d = v[j] - mu; s2 += d * d; }
            s2 += __shfl_xor(s2, 16); s2 += __shfl_xor(s2, 32);
            float rs = rsqrtf(s2 * 0.0078125f + 1e-5f);
            union U8 { bf16x8 v8; unsigned u[4]; };
            bf16x8 afr[4];
            {
                const float* gp = lndg + kgrp * 8;
                const float* bbp = lndb + kgrp * 8;
                #pragma unroll
                for (int ks = 0; ks < 4; ++ks) {
                    float4 g0 = *(const float4*)(gp + ks * 32);
                    float4 g1 = *(const float4*)(gp + ks * 32 + 4);
                    float4 c0 = *(const float4*)(bbp + ks * 32);
                    float4 c1 = *(const float4*)(bbp + ks * 32 + 4);
                    U8 t;
                    t.u[0] = pk_bf16((v[ks*8+0]-mu)*rs*g0.x + c0.x, (v[ks*8+1]-mu)*rs*g0.y + c0.y);
                    t.u[1] = pk_bf16((v[ks*8+2]-mu)*rs*g0.z + c0.z, (v[ks*8+3]-mu)*rs*g0.w + c0.w);
                    t.u[2] = pk_bf16((v[ks*8+4]-mu)*rs*g1.x + c1.x, (v[ks*8+5]-mu)*rs*g1.y + c1.y);
                    t.u[3] = pk_bf16((v[ks*8+6]-mu)*rs*g1.z + c1.z, (v[ks*8+7]-mu)*rs*g1.w + c1.w);
                    afr[ks] = t.v8;
                }
            }
            // ---- GEMM1 (K=128 -> 256) + GELU + GEMM2 (K=256 -> 64), K2-chunked
            f32x4 acc2[4];
            #pragma unroll
            for (int n = 0; n < 4; ++n) acc2[n] = (f32x4){0.f, 0.f, 0.f, 0.f};
            for (int ks2 = 0; ks2 < 8; ++ks2) {
                f32x4 a1v[2];
                a1v[0] = (f32x4){0.f, 0.f, 0.f, 0.f};
                a1v[1] = (f32x4){0.f, 0.f, 0.f, 0.f};
                #pragma unroll
                for (int ks1 = 0; ks1 < 4; ++ks1) {
                    #pragma unroll
                    for (int p = 0; p < 2; ++p) {
                        bf16x8 bf = *(const bf16x8*)(sW1 + (size_t)((((2*ks2+p) << 2) | ks1) * 64 + lane) * 8);
                        a1v[p] = __builtin_amdgcn_mfma_f32_16x16x32_bf16(afr[ks1], bf, a1v[p], 0, 0, 0);
                    }
                }
                #pragma unroll
                for (int p = 0; p < 2; ++p) {
                    float bias = bd1[(2*ks2+p) * 16 + arow];
                    #pragma unroll
                    for (int rr = 0; rr < 4; ++rr) {
                        float vv = gelu(a1v[p][rr] + bias);
                        int row = kgrp * 4 + rr;
                        int byte = row * 64 + (((p * 16 + arow) * 2) ^ ((row & 3) << 4));
                        myb[byte >> 1] = f2bf(vv);
                    }
                }
                bf16x8 af2 = *(const bf16x8*)(myb + ((arow * 64 + ((kgrp * 16) ^ ((arow & 3) << 4))) >> 1));
                #pragma unroll
                for (int n2 = 0; n2 < 4; ++n2) {
                    bf16x8 bf = *(const bf16x8*)(sW2 + (size_t)(((n2 << 3) | ks2) * 64 + lane) * 8);
                    acc2[n2] = __builtin_amdgcn_mfma_f32_16x16x32_bf16(af2, bf, acc2[n2], 0, 0, 0);
                }
            }
            // ---- mid-iteration: issue next tile's meta (list value has landed)
            c_n = pernode[node_n * 8 + gn];
            p8_n = *(const int4*)(bucket + ((size_t)node_n * 8 + gn) * 16);
            // ---- + bd2, LN_u over C=64
            float hv[4][4];
            #pragma unroll
            for (int n2 = 0; n2 < 4; ++n2)
                #pragma unroll
                for (int rr = 0; rr < 4; ++rr)
                    hv[n2][rr] = acc2[n2][rr] + bd2[n2 * 16 + arow];
            float mu_u[4], rs_u[4];
            #pragma unroll
            for (int rr = 0; rr < 4; ++rr) {
                float sr = hv[0][rr] + hv[1][rr] + hv[2][rr] + hv[3][rr];
                sr += __shfl_xor(sr, 1); sr += __shfl_xor(sr, 2);
                sr += __shfl_xor(sr, 4); sr += __shfl_xor(sr, 8);
                mu_u[rr] = sr * 0.015625f;
                float sq = 0.f;
                #pragma unroll
                for (int n2 = 0; n2 < 4; ++n2) { float d = hv[n2][rr] - mu_u[rr]; sq += d * d; }
                sq += __shfl_xor(sq, 1); sq += __shfl_xor(sq, 2);
                sq += __shfl_xor(sq, 4); sq += __shfl_xor(sq, 8);
                rs_u[rr] = rsqrtf(sq * 0.015625f + 1e-5f);
            }
            #pragma unroll
            for (int n2 = 0; n2 < 4; ++n2) {
                int cidx = n2 * 16 + arow;
                float gg = lnug[cidx], bb = lnub[cidx];
                #pragma unroll
                for (int rr = 0; rr < 4; ++rr) {
                    float nv = (hv[n2][rr] - mu_u[rr]) * rs_u[rr] * gg + bb;
                    int row = kgrp * 4 + rr;
                    int byte = row * 128 + ((cidx * 2) ^ ((row & 7) << 4));
                    myb[byte >> 1] = f2bf(nv);
                }
            }
            bf16x8 af3[2];
            #pragma unroll
            for (int ks3 = 0; ks3 < 2; ++ks3)
                af3[ks3] = *(const bf16x8*)(myb + ((arow * 128 + ((ks3 * 64 + kgrp * 16) ^ ((arow & 7) << 4))) >> 1));
            // ---- GEMM3 (K=64 -> 128, B-frags from global/L2) + GELU + GEMM4
            f32x4 acc4[8];
            #pragma unroll
            for (int n = 0; n < 8; ++n) acc4[n] = (f32x4){0.f, 0.f, 0.f, 0.f};
            #pragma unroll
            for (int half = 0; half < 2; ++half) {
                f32x4 a3[4];
                #pragma unroll
                for (int n = 0; n < 4; ++n) a3[n] = (f32x4){0.f, 0.f, 0.f, 0.f};
                #pragma unroll
                for (int ks3 = 0; ks3 < 2; ++ks3) {
                    #pragma unroll
                    for (int n3h = 0; n3h < 4; ++n3h) {
                        int n3 = half * 4 + n3h;
                        bf16x8 bf = *(const bf16x8*)(pW3 + (size_t)(((n3 << 1) | ks3) * 64 + lane) * 8);
                        a3[n3h] = __builtin_amdgcn_mfma_f32_16x16x32_bf16(af3[ks3], bf, a3[n3h], 0, 0, 0);
                    }
                }
                #pragma unroll
                for (int n3h = 0; n3h < 4; ++n3h) {
                    float bias = bu1[(half * 4 + n3h) * 16 + arow];
                    #pragma unroll
                    for (int rr = 0; rr < 4; ++rr) {
                        float vv = gelu(a3[n3h][rr] + bias);
                        int row = kgrp * 4 + rr;
                        int byte = row * 128 + (((n3h * 16 + arow) * 2) ^ ((row & 7) << 4));
                        myb[byte >> 1] = f2bf(vv);
                    }
                }
                #pragma unroll
                for (int k4 = 0; k4 < 2; ++k4) {
                    bf16x8 afu = *(const bf16x8*)(myb + ((arow * 128 + ((k4 * 64 + kgrp * 16) ^ ((arow & 7) << 4))) >> 1));
                    #pragma unroll
                    for (int n4 = 0; n4 < 8; ++n4) {
                        bf16x8 bf = *(const bf16x8*)(sW4 + (size_t)(((n4 << 2) | (half * 2 + k4)) * 64 + lane) * 8);
                        acc4[n4] = __builtin_amdgcn_mfma_f32_16x16x32_bf16(afu, bf, acc4[n4], 0, 0, 0);
                    }
                }
            }
            // ---- epilogue: + bu2, broadcast via shfl'd meta (no re-read)
            #pragma unroll
            for (int rr = 0; rr < 4; ++rr) {
                const int src = kgrp * 4 + rr;
                const int c2  = __shfl(c_c, src);
                const unsigned w0 = (unsigned)__shfl(p8_c.x, src);
                const unsigned w1 = (unsigned)__shfl(p8_c.y, src);
                const unsigned w2 = (unsigned)__shfl(p8_c.z, src);
                const unsigned w3 = (unsigned)__shfl(p8_c.w, src);
                const int nd  = __shfl(node_c, src);
                const int gi2 = row0 + kgrp * 4 + rr;
                if (gi2 >= nrows) continue;
                float vals[8];
                #pragma unroll
                for (int n4 = 0; n4 < 8; ++n4) vals[n4] = acc4[n4][rr] + bu2[n4 * 16 + arow];
                {
                    float* op = out_g + (size_t)(w0 & 0xffff) * DD + arow;
                    #pragma unroll
                    for (int n4 = 0; n4 < 8; ++n4) op[n4 * 16] = vals[n4];
                }
                if (c2 > 1) {
                    float* op = out_g + (size_t)(w0 >> 16) * DD + arow;
                    #pragma unroll
                    for (int n4 = 0; n4 < 8; ++n4) op[n4 * 16] = vals[n4];
                }
                if (c2 > 2) {
                    float* op = out_g + (size_t)(w1 & 0xffff) * DD + arow;
                    #pragma unroll
                    for (int n4 = 0; n4 < 8; ++n4) op[n4 * 16] = vals[n4];
                }
                if (c2 > 3) {
                    float* op = out_g + (size_t)(w1 >> 16) * DD + arow;
                    #pragma unroll
                    for (int n4 = 0; n4 < 8; ++n4) op[n4 * 16] = vals[n4];
                }
                if (__any(c2 > 4)) {
                    if (c2 > 4) {
                        float* op = out_g + (size_t)(w2 & 0xffff) * DD + arow;
                        #pragma unroll
                        for (int n4 = 0; n4 < 8; ++n4) op[n4 * 16] = vals[n4];
                    }
                    if (c2 > 5) {
                        float* op = out_g + (size_t)(w2 >> 16) * DD + arow;
                        #pragma unroll
                        for (int n4 = 0; n4 < 8; ++n4) op[n4 * 16] = vals[n4];
                    }
                    if (c2 > 6) {
                        float* op = out_g + (size_t)(w3 & 0xffff) * DD + arow;
                        #pragma unroll
                        for (int n4 = 0; n4 < 8; ++n4) op[n4 * 16] = vals[n4];
                    }
                    if (c2 > 7) {
                        float* op = out_g + (size_t)(w3 >> 16) * DD + arow;
                        #pragma unroll
                        for (int n4 = 0; n4 < 8; ++n4) op[n4 * 16] = vals[n4];
                    }
                }
                if (__any(c2 > 8)) {
                    const ushort_t* bt = bucket + ((size_t)nd * 8 + g) * 16;
                    for (int j = 8; j < 16; ++j) {
                        if (j < c2) {
                            float* op = out_g + (size_t)bt[j] * DD + arow;
                            #pragma unroll
                            for (int n4 = 0; n4 < 8; ++n4) op[n4 * 16] = vals[n4];
                        }
                    }
                }
            }
        } else {
            // skipped strip: still advance the meta pipeline
            c_n = pernode[node_n * 8 + gn];
            p8_n = *(const int4*)(bucket + ((size_t)node_n * 8 + gn) * 16);
        }
        node_c = node_n; c_c = c_n; p8_c = p8_n;
    }
}

extern "C" void kernel_launch(void* const* d_in, const int* in_sizes, int n_in,
                              void* d_out, int out_size, void* d_ws, size_t ws_size,
                              hipStream_t stream) {
    const float* x       = (const float*)d_in[0];
    const int*   indices = (const int*)d_in[1];
    const float* bd      = (const float*)d_in[2];
    const float* ln_d_g  = (const float*)d_in[3];
    const float* ln_d_b  = (const float*)d_in[4];
    const float* Wd1     = (const float*)d_in[5];
    const float* bd1     = (const float*)d_in[6];
    const float* Wd2     = (const float*)d_in[7];
    const float* bd2     = (const float*)d_in[8];
    const float* ln_u_g  = (const float*)d_in[9];
    const float* ln_u_b  = (const float*)d_in[10];
    const float* Wu1     = (const float*)d_in[11];
    const float* bu1     = (const float*)d_in[12];
    const float* Wu2     = (const float*)d_in[13];
    const float* bu2     = (const float*)d_in[14];
    float* out = (float*)d_out;

    char* ws = (char*)d_ws;
    size_t o = 0;
    auto alloc_b = [&](size_t bytes) { char* p = ws + o; o = (o + bytes + 255) & ~(size_t)255; return p; };
    // pernode + cnts + lists contiguous -> single memset region
    int*      pernode = (int*)alloc_b((size_t)NN * 8 * 4);
    int*      cnts    = (int*)alloc_b(8 * 4);
    int*      lists   = (int*)alloc_b((size_t)8 * NS * 4);
    size_t zero_bytes = (size_t)((char*)lists - (char*)pernode) + (size_t)8 * NS * 4;
    ushort_t* bucket  = (ushort_t*)alloc_b((size_t)NN * 8 * 16 * 2);
    short*    pW1     = (short*)alloc_b((size_t)4096 * 16);
    short*    pW2     = (short*)alloc_b((size_t)2048 * 16);
    short*    pW3     = (short*)alloc_b((size_t)1024 * 16);
    short*    pW4     = (short*)alloc_b((size_t)2048 * 16);

    hipMemsetAsync(pernode, 0, zero_bytes, stream);

    prep_all<<<36, 256, 0, stream>>>(Wd1, Wd2, Wu1, Wu2, pW1, pW2, pW3, pW4);
    flagfill_kernel<<<(G8 * NS + 255) / 256, 256, 0, stream>>>(indices, pernode, bucket);
    compact_kernel<<<dim3((NN + 255) / 256, G8), 256, 0, stream>>>(pernode, lists, cnts);
    fused_kernel<<<256, 1024, 0, stream>>>(x, bd, ln_d_g, ln_d_b, pW1, pW2, pW3, pW4,
                                           bd1, bd2, ln_u_g, ln_u_b, bu1, bu2,
                                           lists, cnts, pernode, bucket, out);
}